// Round 1
// baseline (326.444 us; speedup 1.0000x reference)
//
#include <hip/hip_runtime.h>

typedef unsigned short u16;
typedef u16 u16x4 __attribute__((ext_vector_type(4)));
typedef u16 u16x8 __attribute__((ext_vector_type(8)));
typedef __bf16 bf16x8 __attribute__((ext_vector_type(8)));
typedef float f32x4 __attribute__((ext_vector_type(4)));
typedef float f32x16 __attribute__((ext_vector_type(16)));

static __device__ __forceinline__ u16 f2bf(float f) {
  unsigned u = __builtin_bit_cast(unsigned, f);
  u += 0x7fffu + ((u >> 16) & 1u);   // RNE; finite inputs
  return (u16)(u >> 16);
}
static __device__ __forceinline__ float bf2f(u16 h) {
  return __builtin_bit_cast(float, ((unsigned)h) << 16);
}

// async global->LDS, 16B/lane. LDS dest = wave-uniform base + lane*16.
static __device__ __forceinline__ void gload_lds16(const u16* g, u16* l) {
  u16* gn = const_cast<u16*>(g);
  __builtin_amdgcn_global_load_lds(
      (__attribute__((address_space(1))) unsigned int*)gn,
      (__attribute__((address_space(3))) unsigned int*)l,
      16, 0, 0);
}

__global__ __launch_bounds__(256)
void cvt_f32_bf16(const float* __restrict__ in, u16* __restrict__ out) {
  const int i = blockIdx.x * 256 + threadIdx.x;
  float4 f = ((const float4*)in)[i];
  u16x4 o = { f2bf(f.x), f2bf(f.y), f2bf(f.z), f2bf(f.w) };
  ((u16x4*)out)[i] = o;
}

__global__ __launch_bounds__(256)
void cvt_w3(const float* __restrict__ a, const float* __restrict__ b,
            const float* __restrict__ c, u16* __restrict__ out) {
  const int blk = blockIdx.x;       // 0..3071
  const int w = blk >> 10;
  const float* src = (w == 0) ? a : (w == 1) ? b : c;
  const int i = (blk & 1023) * 256 + threadIdx.x;
  float4 f = ((const float4*)src)[i];
  u16x4 o = { f2bf(f.x), f2bf(f.y), f2bf(f.z), f2bf(f.w) };
  ((u16x4*)(out + (size_t)w * 1048576ULL))[i] = o;
}

// ============================================================================
// 256x256 8-phase GEMM (T2+T3+T4+T5), C[m][n] = sum_k A[m][k]*B[n][k].
// 512 threads = 8 waves in 2(m) x 4(n); per-wave output 128x64 via
// mfma_f32_16x16x32_bf16 (8 m-frags x 4 n-frags). BK=64, double-buffered
// (128 KiB LDS), 2 K-tiles per unrolled iteration = 8 phases.
//
// Staging (wave stages exactly what it reads -> per-wave vmcnt is a full
// clearance proof once followed by s_barrier):
//   A-half wr (128x64, 16KB) staged by the 4 waves with that wr:
//     4 instrs/thread, instr j = rows j*32+wc*8+(lane>>3), LDS linear.
//   B-quarter wc (64x64, 8KB) staged by the 2 waves with that wc:
//     4 instrs/thread, instr (ks,rh) = rows rh*32+wr*16+(lane>>2), ks half of K.
// LDS layouts (linear for global_load_lds; swizzle folded into SOURCE addr):
//   As[buf][half][row 128][k 64] u16, 16B chunk at pos p holds global chunk
//     p ^ (row&7)          -> frag read 2-way conflict (free, m136).
//   Bs[buf][q][ks][row 64][k 32] u16, chunk pos p holds global chunk
//     p ^ ((row>>1)&3)     -> frag read 2-way conflict.
// Phase q of tile t: quadrant (mh,ks) in order (0,0)(0,1)(1,0)(1,1);
// stage order for tile t+1: P0:A{0,1}  P1:B{ks0}  P2:B{ks1}  P3:A{2,3}.
// vmcnt accounting (per wave, 2 loads/phase, 8/tile; counted, never 0):
//   end-P3: out={A01,Bk0,Bk1,A23}(t+1)=8 -> vmcnt(4) clears A01,Bk0 (P0 needs)
//   end-P0: out={Bk1,A23,nA01}=6         -> vmcnt(4) clears Bk1     (P1 needs)
//   end-P1: out={A23,nA01,nBk0}=6        -> vmcnt(4) clears A23     (P2 needs)
//   end-P2: nothing new needed by P3     -> no wait
// Each vmcnt precedes the phase-closing s_barrier => cross-wave safe.
// MODE 0: fused QKV epilogue (Q scaled 1/32); MODE 2: bf16 out, z-strided.
// ============================================================================

#define MM16(a, b, c) __builtin_amdgcn_mfma_f32_16x16x32_bf16(a, b, c, 0, 0, 0)
#define WAITV4 asm volatile("s_waitcnt vmcnt(4)" ::: "memory")
#define WAITNONE (void)0

#define STAGE_A(BUF, J, KT) \
  gload_lds16(Ag + (size_t)(J) * 32 * lda + (KT), AsW + (BUF) * 16384 + (J) * 2048)
#define STAGE_B(BUF, KS, RH, KT) \
  gload_lds16(Bg + (size_t)(RH) * 32 * ldb + (KS) * 32 + (KT), \
              BsW + (BUF) * 16384 + (KS) * 2048 + (RH) * 1024)

#define APTR(BUF, MI, KS) \
  ((const bf16x8*)(ArdBase + (BUF) * 16384 + (MI) * 1024 + ((pA0 ^ ((KS) << 2)) << 3)))
#define BPTR(BUF, NI, KS) \
  ((const bf16x8*)(BrdBase + (BUF) * 16384 + (KS) * 2048 + (NI) * 512))

#define PHASE(BUF, MH, KS, WAITSTMT, ...) do {                              \
    bf16x8 a0 = *APTR(BUF, (MH) * 4 + 0, KS);                               \
    bf16x8 a1 = *APTR(BUF, (MH) * 4 + 1, KS);                               \
    bf16x8 a2 = *APTR(BUF, (MH) * 4 + 2, KS);                               \
    bf16x8 a3 = *APTR(BUF, (MH) * 4 + 3, KS);                               \
    bf16x8 q0 = *BPTR(BUF, 0, KS);                                          \
    bf16x8 q1 = *BPTR(BUF, 1, KS);                                          \
    bf16x8 q2 = *BPTR(BUF, 2, KS);                                          \
    bf16x8 q3 = *BPTR(BUF, 3, KS);                                          \
    __VA_ARGS__;                                                            \
    __builtin_amdgcn_sched_barrier(0);                                      \
    __builtin_amdgcn_s_barrier();                                           \
    __builtin_amdgcn_s_setprio(1);                                          \
    acc[(MH)*4+0][0] = MM16(a0, q0, acc[(MH)*4+0][0]);                      \
    acc[(MH)*4+1][0] = MM16(a1, q0, acc[(MH)*4+1][0]);                      \
    acc[(MH)*4+2][0] = MM16(a2, q0, acc[(MH)*4+2][0]);                      \
    acc[(MH)*4+3][0] = MM16(a3, q0, acc[(MH)*4+3][0]);                      \
    acc[(MH)*4+0][1] = MM16(a0, q1, acc[(MH)*4+0][1]);                      \
    acc[(MH)*4+1][1] = MM16(a1, q1, acc[(MH)*4+1][1]);                      \
    acc[(MH)*4+2][1] = MM16(a2, q1, acc[(MH)*4+2][1]);                      \
    acc[(MH)*4+3][1] = MM16(a3, q1, acc[(MH)*4+3][1]);                      \
    acc[(MH)*4+0][2] = MM16(a0, q2, acc[(MH)*4+0][2]);                      \
    acc[(MH)*4+1][2] = MM16(a1, q2, acc[(MH)*4+1][2]);                      \
    acc[(MH)*4+2][2] = MM16(a2, q2, acc[(MH)*4+2][2]);                      \
    acc[(MH)*4+3][2] = MM16(a3, q2, acc[(MH)*4+3][2]);                      \
    acc[(MH)*4+0][3] = MM16(a0, q3, acc[(MH)*4+0][3]);                      \
    acc[(MH)*4+1][3] = MM16(a1, q3, acc[(MH)*4+1][3]);                      \
    acc[(MH)*4+2][3] = MM16(a2, q3, acc[(MH)*4+2][3]);                      \
    acc[(MH)*4+3][3] = MM16(a3, q3, acc[(MH)*4+3][3]);                      \
    __builtin_amdgcn_s_setprio(0);                                          \
    WAITSTMT;                                                               \
    __builtin_amdgcn_sched_barrier(0);                                      \
    __builtin_amdgcn_s_barrier();                                           \
  } while (0)

template<int MODE>
__global__ __launch_bounds__(512, 2)
void gemm8p(const u16* __restrict__ Ain, const u16* __restrict__ Bin,
            void* __restrict__ Cv,
            const float* __restrict__ b0, const float* __restrict__ b1,
            const float* __restrict__ b2,
            int lda, int ldb, int ldc, int K,
            unsigned long long sA, unsigned long long sB, unsigned long long sC,
            int nbx, int nby)
{
  __shared__ alignas(16) u16 As[2 * 2 * 128 * 64];      // 64 KiB
  __shared__ alignas(16) u16 Bs[2 * 4 * 2 * 64 * 32];   // 64 KiB

  // XCD-chunk + group-m swizzle (grid % 8 == 0 for all call sites)
  const int nbxy = nbx * nby;
  const int bid  = blockIdx.x;
  const int flat = (bid & 7) * ((int)gridDim.x >> 3) + (bid >> 3);
  const int z    = flat / nbxy;
  const int rr   = flat - z * nbxy;
  const int width = nbx << 3;
  const int gid  = rr / width;
  const int rw   = rr - gid * width;
  const int by   = (gid << 3) + (rw & 7);
  const int bx   = rw >> 3;

  const u16* A = Ain + z * sA;
  const u16* B = Bin + z * sB;

  const int tid  = threadIdx.x;
  const int wave = tid >> 6;
  const int lane = tid & 63;
  const int wr   = wave >> 2;     // 0..1  (m)
  const int wc   = wave & 3;      // 0..3  (n)
  const int l16  = lane & 15;
  const int l4   = lane >> 4;

  const int m0 = by << 8;
  const int n0 = bx << 8;

  // --- staging addresses (source carries the inverse swizzle) ---
  const int asr = wc * 8 + (lane >> 3);
  const int asc = ((lane & 7) ^ (lane >> 3)) << 3;
  const u16* Ag = A + (size_t)(m0 + wr * 128 + asr) * lda + asc;
  u16* AsW = As + wr * 8192 + wc * 512;            // + BUF*16384 + j*2048

  const int bsr = wr * 16 + (lane >> 2);
  const int bsc = ((lane & 3) ^ ((lane >> 3) & 3)) << 3;
  const u16* Bg = B + (size_t)(n0 + wc * 64 + bsr) * ldb + bsc;
  u16* BsW = Bs + wc * 4096 + wr * 512;            // + BUF*16384 + ks*2048 + rh*1024

  // --- fragment read bases ---
  const u16* ArdBase = As + (wr * 128 + l16) * 64;           // + BUF*16384 + mi*1024 + pos*8
  const int pA0 = l4 ^ (l16 & 7);
  const u16* BrdBase = Bs + wc * 4096 + l16 * 32 + ((l4 ^ ((l16 >> 1) & 3)) << 3);

  f32x4 acc[8][4];
  #pragma unroll
  for (int i = 0; i < 8; ++i)
    #pragma unroll
    for (int j = 0; j < 4; ++j)
      #pragma unroll
      for (int r = 0; r < 4; ++r)
        acc[i][j][r] = 0.f;

  // prologue: tile 0 -> buf 0, issued in first-use order
  STAGE_A(0, 0, 0); STAGE_A(0, 1, 0);
  STAGE_B(0, 0, 0, 0); STAGE_B(0, 0, 1, 0);
  STAGE_B(0, 1, 0, 0); STAGE_B(0, 1, 1, 0);
  STAGE_A(0, 2, 0); STAGE_A(0, 3, 0);
  WAITV4;
  __builtin_amdgcn_sched_barrier(0);
  __builtin_amdgcn_s_barrier();

  const int NT = K >> 6;   // tiles of BK=64; NT even for all call sites
  for (int t = 0; t < NT; t += 2) {
    {
      const int kn = (t + 1) * 64;
      PHASE(0, 0, 0, WAITV4,   STAGE_A(1, 0, kn); STAGE_A(1, 1, kn));
      PHASE(0, 0, 1, WAITV4,   STAGE_B(1, 0, 0, kn); STAGE_B(1, 0, 1, kn));
      PHASE(0, 1, 0, WAITNONE, STAGE_B(1, 1, 0, kn); STAGE_B(1, 1, 1, kn));
      PHASE(0, 1, 1, WAITV4,   STAGE_A(1, 2, kn); STAGE_A(1, 3, kn));
    }
    {
      const int kn = (t + 2 < NT) ? (t + 2) * 64 : 0;   // last iter: harmless re-stage
      PHASE(1, 0, 0, WAITV4,   STAGE_A(0, 0, kn); STAGE_A(0, 1, kn));
      PHASE(1, 0, 1, WAITV4,   STAGE_B(0, 0, 0, kn); STAGE_B(0, 0, 1, kn));
      PHASE(1, 1, 0, WAITNONE, STAGE_B(0, 1, 0, kn); STAGE_B(0, 1, 1, kn));
      PHASE(1, 1, 1, WAITV4,   STAGE_A(0, 2, kn); STAGE_A(0, 3, kn));
    }
  }
  asm volatile("s_waitcnt vmcnt(0)" ::: "memory");   // drain wrap-stage before LDS dies

  // epilogue: C/D 16x16x32 map: col = lane&15, row = (lane>>4)*4 + reg (m89)
  if constexpr (MODE == 0) {
    const int g = n0 >> 10;                     // 0=Q, 1=K, 2=V (block-uniform)
    const int colb = (n0 + wc * 64) & 1023;
    const int rowb = m0 + wr * 128 + l4 * 4;
    if (g < 2) {
      u16* Cb = (u16*)Cv + (size_t)g * 8388608ULL;
      const float* bp = (g == 0) ? b0 : b1;
      const float qs = (g == 0) ? 0.03125f : 1.0f;   // fold 1/sqrt(1024) into Q
      #pragma unroll
      for (int ni = 0; ni < 4; ++ni) {
        const int col = colb + ni * 16 + l16;
        const float bv = bp[col];
        #pragma unroll
        for (int mi = 0; mi < 8; ++mi) {
          const int row = rowb + mi * 16;
          #pragma unroll
          for (int r = 0; r < 4; ++r)
            Cb[(size_t)(row + r) * 1024 + col] = f2bf((acc[mi][ni][r] + bv) * qs);
        }
      }
    } else {
      u16* Vt = (u16*)Cv + 16777216ULL;         // [4][1024][2048]
      #pragma unroll
      for (int ni = 0; ni < 4; ++ni) {
        const int col = colb + ni * 16 + l16;
        const float bv = b2[col];
        #pragma unroll
        for (int mi = 0; mi < 8; ++mi) {
          const int row = rowb + mi * 16;       // 4 consecutive s via reg idx
          u16x4 o;
          #pragma unroll
          for (int r = 0; r < 4; ++r) o[r] = f2bf(acc[mi][ni][r] + bv);
          const size_t idx = ((size_t)((row >> 11) * 1024 + col)) * 2048 + (row & 2047);
          *(u16x4*)&Vt[idx] = o;
        }
      }
    }
  } else {   // MODE 2: bf16 out, row-major ldc, z-strided
    u16* Cb = (u16*)Cv + (size_t)z * sC;
    #pragma unroll
    for (int ni = 0; ni < 4; ++ni) {
      const int col = n0 + wc * 64 + ni * 16 + l16;
      #pragma unroll
      for (int mi = 0; mi < 8; ++mi) {
        const int row = m0 + wr * 128 + mi * 16 + l4 * 4;
        #pragma unroll
        for (int r = 0; r < 4; ++r)
          Cb[(size_t)(row + r) * ldc + col] = f2bf(acc[mi][ni][r]);
      }
    }
  }
}

// ============================================================================
// legacy 128x128 2-phase kernel (kept for PV: grid 512 keeps all CUs busy;
// a 256-tile PV would only have 128 blocks). 32x32x16 MFMA, 2x2 waves.
// ============================================================================
template<int MODE>
__global__ __launch_bounds__(256)
void gemm_bt(const u16* __restrict__ Ain, const u16* __restrict__ Bin,
             void* __restrict__ Cv,
             const float* __restrict__ b0, const float* __restrict__ b1,
             const float* __restrict__ b2,
             int lda, int ldb, int ldc, int K,
             unsigned long long sA, unsigned long long sB, unsigned long long sC,
             int nbx, int nby)
{
  constexpr int BM = 128, BN = 128, BK = 64;
  __shared__ alignas(16) u16 As[BM * BK];
  __shared__ alignas(16) u16 Bs[BN * BK];

  const int nbxy = nbx * nby;
  const int bid  = blockIdx.x;
  const int flat = (bid & 7) * ((int)gridDim.x >> 3) + (bid >> 3);
  const int z    = flat / nbxy;
  const int rr   = flat - z * nbxy;
  const int width = nbx << 3;
  const int gid  = rr / width;
  const int rw   = rr - gid * width;
  const int by   = (gid << 3) + (rw & 7);
  const int bx   = rw >> 3;

  const u16* A = Ain + z * sA;
  const u16* B = Bin + z * sB;

  const int tid  = threadIdx.x;
  const int wave = tid >> 6;
  const int lane = tid & 63;
  const int l32  = lane & 31;
  const int half = lane >> 5;
  const int wr   = wave >> 1;
  const int wc   = wave & 1;

  const int m0 = by * BM;
  const int n0 = bx * BN;

  const int lr = lane >> 3;
  const int sc = ((lane & 7) ^ lr) * 8;
  const u16* Ag = A + (size_t)(m0 + wave * 32 + lr) * lda + sc;
  const u16* Bg = B + (size_t)(n0 + wave * 32 + lr) * ldb + sc;
  u16* Asb = &As[(wave * 32) * BK];
  u16* Bsb = &Bs[(wave * 32) * BK];

  f32x16 acc[2][2];
  #pragma unroll
  for (int i = 0; i < 2; ++i)
    #pragma unroll
    for (int j = 0; j < 2; ++j)
      #pragma unroll
      for (int r = 0; r < 16; ++r)
        acc[i][j][r] = 0.f;

  for (int k0 = 0; k0 < K; k0 += BK) {
    gload_lds16(Ag + k0,                    Asb);
    gload_lds16(Ag + (size_t) 8 * lda + k0, Asb +  8 * BK);
    gload_lds16(Ag + (size_t)16 * lda + k0, Asb + 16 * BK);
    gload_lds16(Ag + (size_t)24 * lda + k0, Asb + 24 * BK);
    gload_lds16(Bg + k0,                    Bsb);
    gload_lds16(Bg + (size_t) 8 * ldb + k0, Bsb +  8 * BK);
    gload_lds16(Bg + (size_t)16 * ldb + k0, Bsb + 16 * BK);
    gload_lds16(Bg + (size_t)24 * ldb + k0, Bsb + 24 * BK);
    __syncthreads();

    #pragma unroll
    for (int ks = 0; ks < 4; ++ks) {
      bf16x8 af[2], bfr[2];
      #pragma unroll
      for (int ti = 0; ti < 2; ++ti) {
        const int row = wr * 64 + ti * 32 + l32;
        const int ch  = ((ks * 2 + half) ^ (row & 7)) * 8;
        af[ti] = *(const bf16x8*)&As[row * BK + ch];
      }
      #pragma unroll
      for (int tj = 0; tj < 2; ++tj) {
        const int row = wc * 64 + tj * 32 + l32;
        const int ch  = ((ks * 2 + half) ^ (row & 7)) * 8;
        bfr[tj] = *(const bf16x8*)&Bs[row * BK + ch];
      }
      #pragma unroll
      for (int ti = 0; ti < 2; ++ti)
        #pragma unroll
        for (int tj = 0; tj < 2; ++tj)
          acc[ti][tj] = __builtin_amdgcn_mfma_f32_32x32x16_bf16(af[ti], bfr[tj], acc[ti][tj], 0, 0, 0);
    }
    __syncthreads();
  }

  const int colb = n0 + wc * 64 + l32;
  const int rowb = m0 + wr * 64 + 4 * half;

  if constexpr (MODE == 3) {
    float* Cf = (float*)Cv + z * sC;
    #pragma unroll
    for (int tj = 0; tj < 2; ++tj) {
      const int col = colb + tj * 32;
      #pragma unroll
      for (int ti = 0; ti < 2; ++ti)
        #pragma unroll
        for (int g4 = 0; g4 < 4; ++g4)
          #pragma unroll
          for (int r = 0; r < 4; ++r) {
            const int row = rowb + ti * 32 + g4 * 8 + r;
            Cf[(size_t)row * ldc + col] = acc[ti][tj][g4 * 4 + r];
          }
    }
  }
}

// one block per row; reads bf16 logits, writes fp32 attn to d_out and
// bf16 attn in-place (input to the PV gemm).
__global__ __launch_bounds__(256)
void softmax_rows(u16* __restrict__ logits, float* __restrict__ attn) {
  const int row = blockIdx.x;
  const int tid = threadIdx.x;
  u16*   lp = logits + (size_t)row * 2048 + tid * 8;
  float* ap = attn   + (size_t)row * 2048 + tid * 8;

  u16x8 raw = *(const u16x8*)lp;
  float v[8];
  #pragma unroll
  for (int j = 0; j < 8; ++j) v[j] = bf2f(raw[j]);

  float mx = v[0];
  #pragma unroll
  for (int j = 1; j < 8; ++j) mx = fmaxf(mx, v[j]);
  #pragma unroll
  for (int o = 32; o > 0; o >>= 1) mx = fmaxf(mx, __shfl_xor(mx, o, 64));

  __shared__ float smax[4], ssum[4];
  const int wv = tid >> 6, ln = tid & 63;
  if (ln == 0) smax[wv] = mx;
  __syncthreads();
  mx = fmaxf(fmaxf(smax[0], smax[1]), fmaxf(smax[2], smax[3]));

  float s = 0.f;
  #pragma unroll
  for (int j = 0; j < 8; ++j) { v[j] = __expf(v[j] - mx); s += v[j]; }
  #pragma unroll
  for (int o = 32; o > 0; o >>= 1) s += __shfl_xor(s, o, 64);
  if (ln == 0) ssum[wv] = s;
  __syncthreads();
  s = (ssum[0] + ssum[1]) + (ssum[2] + ssum[3]);
  const float inv = 1.f / s;

  u16x8 ob;
  #pragma unroll
  for (int j = 0; j < 8; ++j) { v[j] *= inv; ob[j] = f2bf(v[j]); }
  float4* apv = (float4*)ap;
  apv[0] = make_float4(v[0], v[1], v[2], v[3]);
  apv[1] = make_float4(v[4], v[5], v[6], v[7]);
  *(u16x8*)lp = ob;
}

extern "C" void kernel_launch(void* const* d_in, const int* in_sizes, int n_in,
                              void* d_out, int out_size, void* d_ws, size_t ws_size,
                              hipStream_t stream) {
  (void)in_sizes; (void)n_in; (void)out_size; (void)ws_size;
  const float* x    = (const float*)d_in[0];
  const float* wq_w = (const float*)d_in[1];
  const float* wq_b = (const float*)d_in[2];
  const float* wk_w = (const float*)d_in[3];
  const float* wk_b = (const float*)d_in[4];
  const float* wv_w = (const float*)d_in[5];
  const float* wv_b = (const float*)d_in[6];

  float* attn = (float*)d_out;                 // [4,2048,2048] fp32
  float* outp = attn + 16777216ULL;            // [4,2048,1024] fp32

  // ws layout (u16 elems): x_bf(8M) | wcat(3M) | Q(8M) | K(8M) | V^T(8M) | logits(16M)
  u16* xb   = (u16*)d_ws;
  u16* wcat = xb   + 8388608ULL;
  u16* Qb   = wcat + 3145728ULL;   // [8192][1024], pre-scaled by 1/32
  u16* Kb   = Qb   + 8388608ULL;   // [8192][1024]
  u16* Vt   = Kb   + 8388608ULL;   // [4][1024][2048]
  u16* Lg   = Vt   + 8388608ULL;   // [4][2048][2048]

  cvt_f32_bf16<<<8192, 256, 0, stream>>>(x, xb);
  cvt_w3<<<3072, 256, 0, stream>>>(wq_w, wk_w, wv_w, wcat);

  // fused QKV: M=8192, N=3072, K=1024  (256^2 tiles -> 32x12 = 384 blocks)
  gemm8p<0><<<384, 512, 0, stream>>>(xb, wcat, Qb, wq_b, wk_b, wv_b,
                                     1024, 1024, 1024, 1024, 0, 0, 0, 12, 32);

  // logits = (Q/32) K^T per batch: M=N=2048, K=1024  (8x8x4 = 256 blocks)
  gemm8p<2><<<256, 512, 0, stream>>>(Qb, Kb, Lg, nullptr, nullptr, nullptr,
                                     1024, 1024, 2048, 1024,
                                     2097152ULL, 2097152ULL, 4194304ULL, 8, 8);

  softmax_rows<<<8192, 256, 0, stream>>>(Lg, attn);

  // out = attn V: M=2048, N=1024, K=2048 per batch (legacy 128^2, 512 blocks)
  gemm_bt<3><<<512, 256, 0, stream>>>(Lg, Vt, outp, nullptr, nullptr, nullptr,
                                      2048, 2048, 1024, 2048,
                                      4194304ULL, 2097152ULL, 2097152ULL, 8, 16);
}